// Round 5
// baseline (478.948 us; speedup 1.0000x reference)
//
#include <hip/hip_runtime.h>
#include <math.h>

#define BB 16
#define SS 8192
#define HH 768
#define NH 12
#define HD 64
#define SCALE 0.125f

// ws float offsets
#define WS_QKP   0        // 9216
#define WS_C     9216     // 16
#define WS_GATE  9232     // 768
#define WS_OP    10240    // 16*768
#define WS_POOLED 22528   // 16*12*768
#define WS_STATS 169984   // pm[BB*cpb*NH], pl[BB*cpb*NH], part[BB*cpb*NH*HH]

// ---------------- K0: qkp = scale*Wk^T q (+c), gate ----------------
__global__ __launch_bounds__(256) void k_pre(const float* __restrict__ query,
                                             const float* __restrict__ w_kv,
                                             const float* __restrict__ b_kv,
                                             const float* __restrict__ w_gate,
                                             const float* __restrict__ b_gate,
                                             float* __restrict__ ws) {
    int blk = blockIdx.x, t = threadIdx.x;
    if (blk < 36) {
        int h = blk / 3;
        int j = (blk % 3) * 256 + t;
        float acc = 0.f;
        #pragma unroll 8
        for (int d = 0; d < HD; d++)
            acc += query[h * HD + d] * w_kv[(size_t)(h * HD + d) * HH + j];
        ws[WS_QKP + h * HH + j] = acc * SCALE;
    } else if (blk == 36) {
        if (t < NH) {
            float acc = 0.f;
            for (int d = 0; d < HD; d++)
                acc += query[t * HD + d] * b_kv[t * HD + d];
            ws[WS_C + t] = acc * SCALE;
        }
    } else {
        __shared__ __align__(16) float qs[HH];
        for (int i = t; i < HH; i += 256) qs[i] = query[i];
        __syncthreads();
        int g = blk - 37;
        int wave = t >> 6, lane = t & 63;
        for (int o = 0; o < 16; o++) {
            int i = g * 64 + wave * 16 + o;
            const float* wr = w_gate + (size_t)i * HH + lane * 4;
            float s = 0.f;
            #pragma unroll
            for (int kk = 0; kk < 3; kk++) {
                float4 wv = *(const float4*)(wr + 256 * kk);
                float4 qv = *(const float4*)&qs[lane * 4 + 256 * kk];
                s += wv.x * qv.x + wv.y * qv.y + wv.z * qv.z + wv.w * qv.w;
            }
            #pragma unroll
            for (int off = 1; off < 64; off <<= 1) s += __shfl_xor(s, off, 64);
            if (lane == 0) {
                float z = s + b_gate[i];
                ws[WS_GATE + i] = 1.0f / (1.0f + expf(-z));
            }
        }
    }
}

// ---------------- K1: fused scores + online softmax + pool ----------------
// LDS = qkp only (36 KB) -> 4 blocks/CU. 8-row tiles; phase 2 re-reads tile
// from global (L2-resident: 4 blk/CU * 32 CU * 24 KB = 3 MB/XCD < 4 MB L2).
__global__ __launch_bounds__(256, 4) void k_fused(const float* __restrict__ x,
                                                  const float* __restrict__ ws,
                                                  float* __restrict__ part,
                                                  float* __restrict__ pm,
                                                  float* __restrict__ pl,
                                                  int cpb, int rowsPC) {
    __shared__ __align__(16) float qkp_s[NH * HH];   // 36 KB
    __shared__ float st[8][NH];
    __shared__ float wt[8][NH];
    __shared__ float msh[NH], fsh[NH], lsh[NH], csh[NH];

    int t = threadIdx.x;
    int cblk = blockIdx.x, b = blockIdx.y;
    int wave = t >> 6, lane = t & 63;
    int k = lane & 31, half = lane >> 5;
    int row2 = wave * 2 + half;              // 0..7 within tile

    // stage qkp to LDS (coalesced float4)
    {
        const float4* qg = (const float4*)(ws + WS_QKP);
        float4* qs = (float4*)qkp_s;
        #pragma unroll
        for (int i = 0; i < 9; i++) qs[t + 256 * i] = qg[t + 256 * i];
    }
    if (t < NH) { csh[t] = ws[WS_C + t]; msh[t] = -1e30f; lsh[t] = 0.f; }
    __syncthreads();

    float P[NH][3];
    #pragma unroll
    for (int h = 0; h < NH; h++) { P[h][0] = 0.f; P[h][1] = 0.f; P[h][2] = 0.f; }

    int nt = rowsPC >> 3;
    const float* xb = x + ((size_t)b * SS + (size_t)cblk * rowsPC) * HH;

    for (int tile = 0; tile < nt; tile++) {
        // ---- phase 1: scores; 32 lanes per row, qkp from LDS (broadcast b128) ----
        {
            const float* xr = xb + (size_t)(tile * 8 + row2) * HH + 4 * k;
            float acc[NH];
            #pragma unroll
            for (int h = 0; h < NH; h++) acc[h] = 0.f;
            #pragma unroll
            for (int c2 = 0; c2 < 6; c2++) {
                float4 xq = *(const float4*)(xr + 128 * c2);
                #pragma unroll
                for (int h = 0; h < NH; h++) {
                    float4 qv = *(const float4*)&qkp_s[h * HH + 4 * k + 128 * c2];
                    acc[h] += xq.x * qv.x + xq.y * qv.y + xq.z * qv.z + xq.w * qv.w;
                }
            }
            #pragma unroll
            for (int h = 0; h < NH; h++) {
                float v = acc[h];
                v += __shfl_xor(v, 1, 64); v += __shfl_xor(v, 2, 64);
                v += __shfl_xor(v, 4, 64); v += __shfl_xor(v, 8, 64);
                v += __shfl_xor(v, 16, 64);
                acc[h] = v;
            }
            if (k == 0) {
                #pragma unroll
                for (int h = 0; h < NH; h++) st[row2][h] = acc[h] + csh[h];
            }
        }
        __syncthreads();

        // ---- stats: 96 threads, 8-lane-group reduces ----
        if (t < 96) {
            int rr = t & 7, hh = t >> 3;
            float v = st[rr][hh];
            float m8 = v;
            m8 = fmaxf(m8, __shfl_xor(m8, 1, 64));
            m8 = fmaxf(m8, __shfl_xor(m8, 2, 64));
            m8 = fmaxf(m8, __shfl_xor(m8, 4, 64));
            float mo = msh[hh];
            float mn = fmaxf(mo, m8);
            float f  = __expf(mo - mn);
            float w  = __expf(v - mn);
            wt[rr][hh] = w;
            float sm = w;
            sm += __shfl_xor(sm, 1, 64); sm += __shfl_xor(sm, 2, 64);
            sm += __shfl_xor(sm, 4, 64);
            if (rr == 0) {
                msh[hh] = mn;
                fsh[hh] = f;
                lsh[hh] = lsh[hh] * f + sm;
            }
        }
        __syncthreads();

        // ---- phase 2: rescale P; pool from global (L2-hot) ----
        {
            #pragma unroll
            for (int h = 0; h < NH; h++) {
                float fh = fsh[h];
                P[h][0] *= fh; P[h][1] *= fh; P[h][2] *= fh;
            }
            const float* xp = xb + (size_t)(tile * 8) * HH;
            #pragma unroll 2
            for (int r = 0; r < 8; r++) {
                float x0 = xp[(size_t)r * HH + t];
                float x1 = xp[(size_t)r * HH + 256 + t];
                float x2 = xp[(size_t)r * HH + 512 + t];
                #pragma unroll
                for (int h = 0; h < NH; h++) {
                    float wv = wt[r][h];
                    P[h][0] += wv * x0; P[h][1] += wv * x1; P[h][2] += wv * x2;
                }
            }
        }
        __syncthreads();
    }

    // write partials
    size_t blkc = (size_t)b * cpb + cblk;
    #pragma unroll
    for (int h = 0; h < NH; h++) {
        part[(blkc * NH + h) * HH + 0 * 256 + t] = P[h][0];
        part[(blkc * NH + h) * HH + 1 * 256 + t] = P[h][1];
        part[(blkc * NH + h) * HH + 2 * 256 + t] = P[h][2];
    }
    if (t < NH) { pm[blkc * NH + t] = msh[t]; pl[blkc * NH + t] = lsh[t]; }
}

// ---------------- K2: combine chunk partials -> pooled ----------------
__global__ __launch_bounds__(256) void k_comb(const float* __restrict__ part,
                                              const float* __restrict__ pm,
                                              const float* __restrict__ pl,
                                              float* __restrict__ pooled, int cpb) {
    int h = blockIdx.x, b = blockIdx.y, t = threadIdx.x;
    __shared__ float fac[64];
    __shared__ float Ish;
    float mval = -1e30f, lval = 0.f;
    if (t < cpb) {
        mval = pm[((size_t)b * cpb + t) * NH + h];
        lval = pl[((size_t)b * cpb + t) * NH + h];
    }
    if (t < 64) {
        float m = mval;
        #pragma unroll
        for (int off = 1; off < 64; off <<= 1) m = fmaxf(m, __shfl_xor(m, off, 64));
        float fc = (t < cpb) ? __expf(mval - m) : 0.f;
        fac[t] = fc;
        float l = lval * fc;
        #pragma unroll
        for (int off = 1; off < 64; off <<= 1) l += __shfl_xor(l, off, 64);
        if (t == 0) Ish = 1.0f / l;
    }
    __syncthreads();
    float inv = Ish;
    #pragma unroll
    for (int kk = 0; kk < 3; kk++) {
        int col = kk * 256 + t;
        float s = 0.f;
        for (int c = 0; c < cpb; c++)
            s += part[(((size_t)b * cpb + c) * NH + h) * HH + col] * fac[c];
        pooled[((size_t)b * NH + h) * HH + col] = s * inv;
    }
}

// ---------------- K3: op = W_v pooled + b_v ----------------
__global__ __launch_bounds__(256) void k_v(const float* __restrict__ pooled,
                                           const float* __restrict__ w_kv,
                                           const float* __restrict__ b_kv,
                                           float* __restrict__ op) {
    int seg = blockIdx.x, b = blockIdx.y, t = threadIdx.x;
    __shared__ __align__(16) float pv[1536];
    for (int i = t; i < 1536; i += 256)
        pv[i] = pooled[((size_t)b * NH + seg * 2) * HH + i];
    __syncthreads();
    int wave = t >> 6, lane = t & 63;
    int lh = wave >> 1;
    for (int o = 0; o < 32; o++) {
        int hd = seg * 128 + wave * 32 + o;
        const float* wr = w_kv + (size_t)(HH + hd) * HH + lane * 4;
        float s = 0.f;
        #pragma unroll
        for (int kk = 0; kk < 3; kk++) {
            float4 wv = *(const float4*)(wr + 256 * kk);
            float4 qv = *(const float4*)&pv[lh * HH + lane * 4 + 256 * kk];
            s += wv.x * qv.x + wv.y * qv.y + wv.z * qv.z + wv.w * qv.w;
        }
        #pragma unroll
        for (int off = 1; off < 64; off <<= 1) s += __shfl_xor(s, off, 64);
        if (lane == 0) op[(size_t)b * HH + hd] = s + b_kv[HH + hd];
    }
}

// ---------------- K4: out = gate * (W_out op + b_out) ----------------
__global__ __launch_bounds__(256) void k_fin(const float* __restrict__ op_in,
                                             const float* __restrict__ w_out,
                                             const float* __restrict__ b_out,
                                             const float* __restrict__ gate,
                                             float* __restrict__ out) {
    int seg = blockIdx.x, b = blockIdx.y, t = threadIdx.x;
    __shared__ __align__(16) float ov[HH];
    for (int i = t; i < HH; i += 256) ov[i] = op_in[(size_t)b * HH + i];
    __syncthreads();
    int wave = t >> 6, lane = t & 63;
    for (int o = 0; o < 32; o++) {
        int i = seg * 128 + wave * 32 + o;
        const float* wr = w_out + (size_t)i * HH + lane * 4;
        float s = 0.f;
        #pragma unroll
        for (int kk = 0; kk < 3; kk++) {
            float4 wv = *(const float4*)(wr + 256 * kk);
            float4 qv = *(const float4*)&ov[lane * 4 + 256 * kk];
            s += wv.x * qv.x + wv.y * qv.y + wv.z * qv.z + wv.w * qv.w;
        }
        #pragma unroll
        for (int off = 1; off < 64; off <<= 1) s += __shfl_xor(s, off, 64);
        if (lane == 0) out[(size_t)b * HH + i] = gate[i] * (s + b_out[i]);
    }
}

extern "C" void kernel_launch(void* const* d_in, const int* in_sizes, int n_in,
                              void* d_out, int out_size, void* d_ws, size_t ws_size,
                              hipStream_t stream) {
    const float* x      = (const float*)d_in[0];
    const float* query  = (const float*)d_in[1];
    const float* w_kv   = (const float*)d_in[2];
    const float* b_kv   = (const float*)d_in[3];
    const float* w_out  = (const float*)d_in[4];
    const float* b_out  = (const float*)d_in[5];
    const float* w_gate = (const float*)d_in[6];
    const float* b_gate = (const float*)d_in[7];
    float* ws  = (float*)d_ws;
    float* out = (float*)d_out;

    size_t need64 = ((size_t)WS_STATS + 2 * (size_t)BB * 64 * NH + (size_t)BB * 64 * NH * HH) * 4;
    int cpb = (ws_size >= need64) ? 64 : 32;    // 64 -> 1024 blocks = 4/CU exactly
    int rowsPC = SS / cpb;

    float* gate   = ws + WS_GATE;
    float* opbuf  = ws + WS_OP;
    float* pooled = ws + WS_POOLED;
    float* pm     = ws + WS_STATS;
    float* pl     = pm + (size_t)BB * cpb * NH;
    float* part   = pl + (size_t)BB * cpb * NH;

    k_pre<<<49, 256, 0, stream>>>(query, w_kv, b_kv, w_gate, b_gate, ws);
    k_fused<<<dim3(cpb, BB), 256, 0, stream>>>(x, ws, part, pm, pl, cpb, rowsPC);
    k_comb<<<dim3(NH, BB), 256, 0, stream>>>(part, pm, pl, pooled, cpb);
    k_v<<<dim3(6, BB), 256, 0, stream>>>(pooled, w_kv, b_kv, opbuf);
    k_fin<<<dim3(6, BB), 256, 0, stream>>>(opbuf, w_out, b_out, gate, out);
}

// Round 6
// 466.984 us; speedup vs baseline: 1.0256x; 1.0256x over previous
//
#include <hip/hip_runtime.h>
#include <math.h>

#define BB 16
#define SS 8192
#define HH 768
#define NH 12
#define HD 64
#define SCALE 0.125f

// ws float offsets
#define WS_QKP   0        // 9216
#define WS_C     9216     // 16
#define WS_GATE  9232     // 768
#define WS_OP    10240    // 16*768
#define WS_POOLED 22528   // 16*12*768
#define WS_STATS 169984   // pm[BB*cpb*NH], pl[BB*cpb*NH], part[BB*cpb*NH*HH]

// DPP rotate-reduce within 16-lane rows (VALU pipe, not LDS)
template<int CTRL>
__device__ __forceinline__ float dpp_add(float x) {
    int r = __builtin_amdgcn_update_dpp(0, __float_as_int(x), CTRL, 0xF, 0xF, true);
    return x + __int_as_float(r);
}
__device__ __forceinline__ float row16_sum(float x) {
    x = dpp_add<0x121>(x);   // row_ror:1
    x = dpp_add<0x122>(x);   // row_ror:2
    x = dpp_add<0x124>(x);   // row_ror:4
    x = dpp_add<0x128>(x);   // row_ror:8
    return x;                // every lane = sum of its 16-lane row
}

// ---------------- K0: qkp = scale*Wk^T q (+c), gate ----------------
__global__ __launch_bounds__(256) void k_pre(const float* __restrict__ query,
                                             const float* __restrict__ w_kv,
                                             const float* __restrict__ b_kv,
                                             const float* __restrict__ w_gate,
                                             const float* __restrict__ b_gate,
                                             float* __restrict__ ws) {
    int blk = blockIdx.x, t = threadIdx.x;
    if (blk < 36) {
        int h = blk / 3;
        int j = (blk % 3) * 256 + t;
        float acc = 0.f;
        #pragma unroll 8
        for (int d = 0; d < HD; d++)
            acc += query[h * HD + d] * w_kv[(size_t)(h * HD + d) * HH + j];
        ws[WS_QKP + h * HH + j] = acc * SCALE;
    } else if (blk == 36) {
        if (t < NH) {
            float acc = 0.f;
            for (int d = 0; d < HD; d++)
                acc += query[t * HD + d] * b_kv[t * HD + d];
            ws[WS_C + t] = acc * SCALE;
        }
    } else {
        __shared__ __align__(16) float qs[HH];
        for (int i = t; i < HH; i += 256) qs[i] = query[i];
        __syncthreads();
        int g = blk - 37;
        int wave = t >> 6, lane = t & 63;
        for (int o = 0; o < 16; o++) {
            int i = g * 64 + wave * 16 + o;
            const float* wr = w_gate + (size_t)i * HH + lane * 4;
            float s = 0.f;
            #pragma unroll
            for (int kk = 0; kk < 3; kk++) {
                float4 wv = *(const float4*)(wr + 256 * kk);
                float4 qv = *(const float4*)&qs[lane * 4 + 256 * kk];
                s += wv.x * qv.x + wv.y * qv.y + wv.z * qv.z + wv.w * qv.w;
            }
            #pragma unroll
            for (int off = 1; off < 64; off <<= 1) s += __shfl_xor(s, off, 64);
            if (lane == 0) {
                float z = s + b_gate[i];
                ws[WS_GATE + i] = 1.0f / (1.0f + expf(-z));
            }
        }
    }
}

// ---------------- K1: fused scores + online softmax + pool ----------------
// 8-row tiles. Phase 1: each wave scores 2 rows (64 lanes across cols),
// qkp from LDS b128 (amortized over 2 rows), DPP rotate-reduce -> st4 partials.
// Phase 2: pool from global (L2-hot 24 KB window).
__global__ __launch_bounds__(256, 3) void k_fused(const float* __restrict__ x,
                                                  const float* __restrict__ ws,
                                                  float* __restrict__ part,
                                                  float* __restrict__ pm,
                                                  float* __restrict__ pl,
                                                  int cpb, int rowsPC) {
    __shared__ __align__(16) float qkp_s[NH * HH];   // 36 KB
    __shared__ __align__(16) float st4[8][NH][4];    // 4 16-lane partial sums
    __shared__ __align__(16) float wt[8][NH];
    __shared__ float msh[NH], fsh[NH], lsh[NH], csh[NH];

    int t = threadIdx.x;
    int cblk = blockIdx.x, b = blockIdx.y;
    int wave = t >> 6, lane = t & 63;

    // stage qkp to LDS (coalesced float4)
    {
        const float4* qg = (const float4*)(ws + WS_QKP);
        float4* qs = (float4*)qkp_s;
        #pragma unroll
        for (int i = 0; i < 9; i++) qs[t + 256 * i] = qg[t + 256 * i];
    }
    if (t < NH) { csh[t] = ws[WS_C + t]; msh[t] = -1e30f; lsh[t] = 0.f; }
    __syncthreads();

    float P[NH][3];
    #pragma unroll
    for (int h = 0; h < NH; h++) { P[h][0] = 0.f; P[h][1] = 0.f; P[h][2] = 0.f; }

    int nt = rowsPC >> 3;
    const float* xb = x + ((size_t)b * SS + (size_t)cblk * rowsPC) * HH;

    for (int tile = 0; tile < nt; tile++) {
        // ---- phase 1: two rows per wave, 64 lanes across 768 cols ----
        {
            const float* xr0 = xb + (size_t)(tile * 8 + 2 * wave) * HH + 4 * lane;
            const float* xr1 = xr0 + HH;
            float4 xa[3], xc[3];
            #pragma unroll
            for (int c2 = 0; c2 < 3; c2++) {
                xa[c2] = *(const float4*)(xr0 + 256 * c2);
                xc[c2] = *(const float4*)(xr1 + 256 * c2);
            }
            float accA[NH], accB[NH];
            #pragma unroll
            for (int h = 0; h < NH; h++) { accA[h] = 0.f; accB[h] = 0.f; }
            #pragma unroll
            for (int c2 = 0; c2 < 3; c2++) {
                #pragma unroll
                for (int h = 0; h < NH; h++) {
                    float4 qv = *(const float4*)&qkp_s[h * HH + 4 * lane + 256 * c2];
                    accA[h] += xa[c2].x * qv.x + xa[c2].y * qv.y + xa[c2].z * qv.z + xa[c2].w * qv.w;
                    accB[h] += xc[c2].x * qv.x + xc[c2].y * qv.y + xc[c2].z * qv.z + xc[c2].w * qv.w;
                }
            }
            int part16 = lane >> 4;
            bool lead = (lane & 15) == 0;
            #pragma unroll
            for (int h = 0; h < NH; h++) {
                float sA = row16_sum(accA[h]);
                float sB = row16_sum(accB[h]);
                if (lead) {
                    st4[2 * wave][h][part16]     = sA;
                    st4[2 * wave + 1][h][part16] = sB;
                }
            }
        }
        __syncthreads();

        // ---- stats: 96 threads; combine 4 partials, 8-lane-group online softmax ----
        if (t < 96) {
            int rr = t & 7, hh = t >> 3;
            float4 p4 = *(const float4*)&st4[rr][hh][0];
            float v = p4.x + p4.y + p4.z + p4.w + csh[hh];
            float m8 = v;
            m8 = fmaxf(m8, __shfl_xor(m8, 1, 64));
            m8 = fmaxf(m8, __shfl_xor(m8, 2, 64));
            m8 = fmaxf(m8, __shfl_xor(m8, 4, 64));
            float mo = msh[hh];
            float mn = fmaxf(mo, m8);
            float f  = __expf(mo - mn);
            float w  = __expf(v - mn);
            wt[rr][hh] = w;
            float sm = w;
            sm += __shfl_xor(sm, 1, 64); sm += __shfl_xor(sm, 2, 64);
            sm += __shfl_xor(sm, 4, 64);
            if (rr == 0) {
                msh[hh] = mn;
                fsh[hh] = f;
                lsh[hh] = lsh[hh] * f + sm;
            }
        }
        __syncthreads();

        // ---- phase 2: rescale P; pool from global (L2-hot tile) ----
        {
            #pragma unroll
            for (int h = 0; h < NH; h++) {
                float fh = fsh[h];
                P[h][0] *= fh; P[h][1] *= fh; P[h][2] *= fh;
            }
            const float* xp = xb + (size_t)(tile * 8) * HH;
            #pragma unroll
            for (int r = 0; r < 8; r++) {
                float4 w0 = *(const float4*)&wt[r][0];
                float4 w4 = *(const float4*)&wt[r][4];
                float4 w8 = *(const float4*)&wt[r][8];
                float x0 = xp[(size_t)r * HH + t];
                float x1 = xp[(size_t)r * HH + 256 + t];
                float x2 = xp[(size_t)r * HH + 512 + t];
                P[0][0] += w0.x * x0; P[0][1] += w0.x * x1; P[0][2] += w0.x * x2;
                P[1][0] += w0.y * x0; P[1][1] += w0.y * x1; P[1][2] += w0.y * x2;
                P[2][0] += w0.z * x0; P[2][1] += w0.z * x1; P[2][2] += w0.z * x2;
                P[3][0] += w0.w * x0; P[3][1] += w0.w * x1; P[3][2] += w0.w * x2;
                P[4][0] += w4.x * x0; P[4][1] += w4.x * x1; P[4][2] += w4.x * x2;
                P[5][0] += w4.y * x0; P[5][1] += w4.y * x1; P[5][2] += w4.y * x2;
                P[6][0] += w4.z * x0; P[6][1] += w4.z * x1; P[6][2] += w4.z * x2;
                P[7][0] += w4.w * x0; P[7][1] += w4.w * x1; P[7][2] += w4.w * x2;
                P[8][0] += w8.x * x0; P[8][1] += w8.x * x1; P[8][2] += w8.x * x2;
                P[9][0] += w8.y * x0; P[9][1] += w8.y * x1; P[9][2] += w8.y * x2;
                P[10][0] += w8.z * x0; P[10][1] += w8.z * x1; P[10][2] += w8.z * x2;
                P[11][0] += w8.w * x0; P[11][1] += w8.w * x1; P[11][2] += w8.w * x2;
            }
        }
        __syncthreads();
    }

    // write partials
    size_t blkc = (size_t)b * cpb + cblk;
    #pragma unroll
    for (int h = 0; h < NH; h++) {
        part[(blkc * NH + h) * HH + 0 * 256 + t] = P[h][0];
        part[(blkc * NH + h) * HH + 1 * 256 + t] = P[h][1];
        part[(blkc * NH + h) * HH + 2 * 256 + t] = P[h][2];
    }
    if (t < NH) { pm[blkc * NH + t] = msh[t]; pl[blkc * NH + t] = lsh[t]; }
}

// ---------------- K2: combine chunk partials -> pooled ----------------
__global__ __launch_bounds__(256) void k_comb(const float* __restrict__ part,
                                              const float* __restrict__ pm,
                                              const float* __restrict__ pl,
                                              float* __restrict__ pooled, int cpb) {
    int h = blockIdx.x, b = blockIdx.y, t = threadIdx.x;
    __shared__ float fac[64];
    __shared__ float Ish;
    float mval = -1e30f, lval = 0.f;
    if (t < cpb) {
        mval = pm[((size_t)b * cpb + t) * NH + h];
        lval = pl[((size_t)b * cpb + t) * NH + h];
    }
    if (t < 64) {
        float m = mval;
        #pragma unroll
        for (int off = 1; off < 64; off <<= 1) m = fmaxf(m, __shfl_xor(m, off, 64));
        float fc = (t < cpb) ? __expf(mval - m) : 0.f;
        fac[t] = fc;
        float l = lval * fc;
        #pragma unroll
        for (int off = 1; off < 64; off <<= 1) l += __shfl_xor(l, off, 64);
        if (t == 0) Ish = 1.0f / l;
    }
    __syncthreads();
    float inv = Ish;
    #pragma unroll
    for (int kk = 0; kk < 3; kk++) {
        int col = kk * 256 + t;
        float s = 0.f;
        for (int c = 0; c < cpb; c++)
            s += part[(((size_t)b * cpb + c) * NH + h) * HH + col] * fac[c];
        pooled[((size_t)b * NH + h) * HH + col] = s * inv;
    }
}

// ---------------- K3: op = W_v pooled + b_v ----------------
__global__ __launch_bounds__(256) void k_v(const float* __restrict__ pooled,
                                           const float* __restrict__ w_kv,
                                           const float* __restrict__ b_kv,
                                           float* __restrict__ op) {
    int seg = blockIdx.x, b = blockIdx.y, t = threadIdx.x;
    __shared__ __align__(16) float pv[1536];
    for (int i = t; i < 1536; i += 256)
        pv[i] = pooled[((size_t)b * NH + seg * 2) * HH + i];
    __syncthreads();
    int wave = t >> 6, lane = t & 63;
    int lh = wave >> 1;
    for (int o = 0; o < 32; o++) {
        int hd = seg * 128 + wave * 32 + o;
        const float* wr = w_kv + (size_t)(HH + hd) * HH + lane * 4;
        float s = 0.f;
        #pragma unroll
        for (int kk = 0; kk < 3; kk++) {
            float4 wv = *(const float4*)(wr + 256 * kk);
            float4 qv = *(const float4*)&pv[lh * HH + lane * 4 + 256 * kk];
            s += wv.x * qv.x + wv.y * qv.y + wv.z * qv.z + wv.w * qv.w;
        }
        #pragma unroll
        for (int off = 1; off < 64; off <<= 1) s += __shfl_xor(s, off, 64);
        if (lane == 0) op[(size_t)b * HH + hd] = s + b_kv[HH + hd];
    }
}

// ---------------- K4: out = gate * (W_out op + b_out) ----------------
__global__ __launch_bounds__(256) void k_fin(const float* __restrict__ op_in,
                                             const float* __restrict__ w_out,
                                             const float* __restrict__ b_out,
                                             const float* __restrict__ gate,
                                             float* __restrict__ out) {
    int seg = blockIdx.x, b = blockIdx.y, t = threadIdx.x;
    __shared__ __align__(16) float ov[HH];
    for (int i = t; i < HH; i += 256) ov[i] = op_in[(size_t)b * HH + i];
    __syncthreads();
    int wave = t >> 6, lane = t & 63;
    for (int o = 0; o < 32; o++) {
        int i = seg * 128 + wave * 32 + o;
        const float* wr = w_out + (size_t)i * HH + lane * 4;
        float s = 0.f;
        #pragma unroll
        for (int kk = 0; kk < 3; kk++) {
            float4 wv = *(const float4*)(wr + 256 * kk);
            float4 qv = *(const float4*)&ov[lane * 4 + 256 * kk];
            s += wv.x * qv.x + wv.y * qv.y + wv.z * qv.z + wv.w * qv.w;
        }
        #pragma unroll
        for (int off = 1; off < 64; off <<= 1) s += __shfl_xor(s, off, 64);
        if (lane == 0) out[(size_t)b * HH + i] = gate[i] * (s + b_out[i]);
    }
}

extern "C" void kernel_launch(void* const* d_in, const int* in_sizes, int n_in,
                              void* d_out, int out_size, void* d_ws, size_t ws_size,
                              hipStream_t stream) {
    const float* x      = (const float*)d_in[0];
    const float* query  = (const float*)d_in[1];
    const float* w_kv   = (const float*)d_in[2];
    const float* b_kv   = (const float*)d_in[3];
    const float* w_out  = (const float*)d_in[4];
    const float* b_out  = (const float*)d_in[5];
    const float* w_gate = (const float*)d_in[6];
    const float* b_gate = (const float*)d_in[7];
    float* ws  = (float*)d_ws;
    float* out = (float*)d_out;

    size_t need64 = ((size_t)WS_STATS + 2 * (size_t)BB * 64 * NH + (size_t)BB * 64 * NH * HH) * 4;
    int cpb = (ws_size >= need64) ? 64 : 32;
    int rowsPC = SS / cpb;

    float* gate   = ws + WS_GATE;
    float* opbuf  = ws + WS_OP;
    float* pooled = ws + WS_POOLED;
    float* pm     = ws + WS_STATS;
    float* pl     = pm + (size_t)BB * cpb * NH;
    float* part   = pl + (size_t)BB * cpb * NH;

    k_pre<<<49, 256, 0, stream>>>(query, w_kv, b_kv, w_gate, b_gate, ws);
    k_fused<<<dim3(cpb, BB), 256, 0, stream>>>(x, ws, part, pm, pl, cpb, rowsPC);
    k_comb<<<dim3(NH, BB), 256, 0, stream>>>(part, pm, pl, pooled, cpb);
    k_v<<<dim3(6, BB), 256, 0, stream>>>(pooled, w_kv, b_kv, opbuf);
    k_fin<<<dim3(6, BB), 256, 0, stream>>>(opbuf, w_out, b_out, gate, out);
}

// Round 8
// 229.117 us; speedup vs baseline: 2.0904x; 2.0382x over previous
//
#include <hip/hip_runtime.h>
#include <math.h>

#define BB 16
#define SS 8192
#define HH 768
#define NH 12
#define HD 64
#define SCALE 0.125f
#define CPB 48            // 768 blocks = 3/CU; chunks: 16x22 + 32x21 tiles of 8 rows

// ws float offsets
#define WS_QKP   0        // 9216
#define WS_C     9216     // 16
#define WS_GATE  9232     // 768
#define WS_OP    10240    // 16*768
#define WS_POOLED 22528   // 16*12*768
#define WS_STATS 169984   // pm[BB*CPB*NH], pl[BB*CPB*NH], part[BB*CPB*NH*HH]

// async global->LDS, 16B per lane; lds dest is wave-uniform base (+lane*16 in HW)
#define GLL(g, l) __builtin_amdgcn_global_load_lds(                      \
    (const __attribute__((address_space(1))) void*)(g),                  \
    (__attribute__((address_space(3))) void*)(l), 16, 0, 0)

__device__ __forceinline__ float dot4(float4 a, float4 b) {
    return a.x * b.x + a.y * b.y + a.z * b.z + a.w * b.w;
}

// DPP rotate-add within 16-lane rows (VALU pipe)
template<int CTRL>
__device__ __forceinline__ float dpp_add(float x) {
    int r = __builtin_amdgcn_update_dpp(0, __float_as_int(x), CTRL, 0xF, 0xF, true);
    return x + __int_as_float(r);
}
__device__ __forceinline__ float sum16(float x) {
    x = dpp_add<0x121>(x);   // row_ror:1
    x = dpp_add<0x122>(x);   // row_ror:2
    x = dpp_add<0x124>(x);   // row_ror:4
    x = dpp_add<0x128>(x);   // row_ror:8
    return x;                // every lane = sum over its 16-lane group
}

// ---------------- K0: qkp = scale*Wk^T q (+c), gate ----------------
__global__ __launch_bounds__(256) void k_pre(const float* __restrict__ query,
                                             const float* __restrict__ w_kv,
                                             const float* __restrict__ b_kv,
                                             const float* __restrict__ w_gate,
                                             const float* __restrict__ b_gate,
                                             float* __restrict__ ws) {
    int blk = blockIdx.x, t = threadIdx.x;
    if (blk < 36) {
        int h = blk / 3;
        int j = (blk % 3) * 256 + t;
        float acc = 0.f;
        #pragma unroll 8
        for (int d = 0; d < HD; d++)
            acc += query[h * HD + d] * w_kv[(size_t)(h * HD + d) * HH + j];
        ws[WS_QKP + h * HH + j] = acc * SCALE;
    } else if (blk == 36) {
        if (t < NH) {
            float acc = 0.f;
            for (int d = 0; d < HD; d++)
                acc += query[t * HD + d] * b_kv[t * HD + d];
            ws[WS_C + t] = acc * SCALE;
        }
    } else {
        // gate: 96 blocks, 8 rows each (2 per wave)
        __shared__ __align__(16) float qs[HH];
        for (int i = t; i < HH; i += 256) qs[i] = query[i];
        __syncthreads();
        int base = (blk - 37) * 8;
        int wave = t >> 6, lane = t & 63;
        #pragma unroll
        for (int o = 0; o < 2; o++) {
            int i = base + wave * 2 + o;
            const float* wr = w_gate + (size_t)i * HH + lane * 4;
            float s = 0.f;
            #pragma unroll
            for (int kk = 0; kk < 3; kk++) {
                float4 wv = *(const float4*)(wr + 256 * kk);
                float4 qv = *(const float4*)&qs[lane * 4 + 256 * kk];
                s += dot4(wv, qv);
            }
            #pragma unroll
            for (int off = 1; off < 64; off <<= 1) s += __shfl_xor(s, off, 64);
            if (lane == 0) {
                float z = s + b_gate[i];
                ws[WS_GATE + i] = 1.0f / (1.0f + expf(-z));
            }
        }
    }
}

// ---------------- K1: fused scores + online softmax + pool ----------------
// Wave w owns heads 3w..3w+2; its qkp slices live in 36 registers (loaded once).
// 8-row x tiles double-buffered in LDS via global_load_lds (width 16).
__global__ __launch_bounds__(256, 2) void k_fused(const float* __restrict__ x,
                                                  const float* __restrict__ ws,
                                                  float* __restrict__ part,
                                                  float* __restrict__ pm,
                                                  float* __restrict__ pl) {
    __shared__ __align__(16) float xt[2][8 * HH];     // 48 KB
    __shared__ __align__(16) float st16[8 * NH * 4];  // 1.5 KB partials
    __shared__ __align__(16) float wt[8 * NH];
    __shared__ float msh[NH], fsh[NH], lsh[NH], csh[NH];

    int t = threadIdx.x;
    int cblk = blockIdx.x, b = blockIdx.y;
    int wave = t >> 6, lane = t & 63;

    // qkp for this wave's 3 heads at this lane's fixed col slice -> registers
    float4 qr[3][3];
    #pragma unroll
    for (int j = 0; j < 3; j++)
        #pragma unroll
        for (int c2 = 0; c2 < 3; c2++)
            qr[j][c2] = *(const float4*)(ws + WS_QKP + (3 * wave + j) * HH + 4 * lane + 256 * c2);
    if (t < NH) { csh[t] = ws[WS_C + t]; msh[t] = -1e30f; lsh[t] = 0.f; }

    float P[NH][3];
    #pragma unroll
    for (int h = 0; h < NH; h++) { P[h][0] = 0.f; P[h][1] = 0.f; P[h][2] = 0.f; }

    int nt    = (cblk < 16) ? 22 : 21;
    int tile0 = (cblk < 16) ? cblk * 22 : 352 + (cblk - 16) * 21;
    const float* xb = x + ((size_t)b * SS + (size_t)tile0 * 8) * HH;

    // prologue: stage tile 0 -> buf 0 (each wave stages its 2 rows)
    {
        const float* g = xb + (size_t)(2 * wave) * HH + 4 * lane;
        float* l = &xt[0][(2 * wave) * HH];
        GLL(g, l);            GLL(g + 256, l + 256);           GLL(g + 512, l + 512);
        GLL(g + HH, l + HH);  GLL(g + HH + 256, l + HH + 256); GLL(g + HH + 512, l + HH + 512);
    }
    __syncthreads();   // drains vmcnt -> tile 0 resident

    for (int tile = 0; tile < nt; tile++) {
        int cur = tile & 1;
        // stage tile+1 into the other buffer (drained by the next __syncthreads)
        if (tile + 1 < nt) {
            const float* g = xb + ((size_t)(tile + 1) * 8 + 2 * wave) * HH + 4 * lane;
            float* l = &xt[cur ^ 1][(2 * wave) * HH];
            GLL(g, l);            GLL(g + 256, l + 256);           GLL(g + 512, l + 512);
            GLL(g + HH, l + HH);  GLL(g + HH + 256, l + HH + 256); GLL(g + HH + 512, l + HH + 512);
        }
        const float* xc = xt[cur];

        // ---- scores: 3 heads x 8 rows per wave; qkp from regs, x from LDS ----
        #pragma unroll
        for (int r = 0; r < 8; r++) {
            float4 x0 = *(const float4*)&xc[r * HH + 4 * lane];
            float4 x1 = *(const float4*)&xc[r * HH + 4 * lane + 256];
            float4 x2 = *(const float4*)&xc[r * HH + 4 * lane + 512];
            float s0 = dot4(x0, qr[0][0]) + dot4(x1, qr[0][1]) + dot4(x2, qr[0][2]);
            float s1 = dot4(x0, qr[1][0]) + dot4(x1, qr[1][1]) + dot4(x2, qr[1][2]);
            float s2 = dot4(x0, qr[2][0]) + dot4(x1, qr[2][1]) + dot4(x2, qr[2][2]);
            s0 = sum16(s0); s1 = sum16(s1); s2 = sum16(s2);
            if ((lane & 15) == 0) {
                int p = lane >> 4;
                st16[(r * NH + 3 * wave + 0) * 4 + p] = s0;
                st16[(r * NH + 3 * wave + 1) * 4 + p] = s1;
                st16[(r * NH + 3 * wave + 2) * 4 + p] = s2;
            }
        }
        __syncthreads();   // st16 visible; tile+1 stage drained

        // ---- stats: 96 threads; combine 4 partials, online softmax update ----
        if (t < 96) {
            int rr = t & 7, hh = t >> 3;
            float4 p4 = *(const float4*)&st16[(rr * NH + hh) * 4];
            float v = (p4.x + p4.y) + (p4.z + p4.w) + csh[hh];
            float m8 = v;
            m8 = fmaxf(m8, __shfl_xor(m8, 1, 64));
            m8 = fmaxf(m8, __shfl_xor(m8, 2, 64));
            m8 = fmaxf(m8, __shfl_xor(m8, 4, 64));
            float mo = msh[hh];
            float mn = fmaxf(mo, m8);
            float f  = __expf(mo - mn);
            float w  = __expf(v - mn);
            wt[rr * NH + hh] = w;
            float sm = w;
            sm += __shfl_xor(sm, 1, 64);
            sm += __shfl_xor(sm, 2, 64);
            sm += __shfl_xor(sm, 4, 64);
            if (rr == 0) { msh[hh] = mn; fsh[hh] = f; lsh[hh] = lsh[hh] * f + sm; }
        }
        __syncthreads();

        // ---- phase 2: rescale P; pool from LDS tile ----
        #pragma unroll
        for (int h = 0; h < NH; h++) {
            float fh = fsh[h];
            P[h][0] *= fh; P[h][1] *= fh; P[h][2] *= fh;
        }
        #pragma unroll
        for (int r = 0; r < 8; r++) {
            float4 w0 = *(const float4*)&wt[r * NH + 0];
            float4 w4 = *(const float4*)&wt[r * NH + 4];
            float4 w8 = *(const float4*)&wt[r * NH + 8];
            float x0 = xc[r * HH + t];
            float x1 = xc[r * HH + 256 + t];
            float x2 = xc[r * HH + 512 + t];
            P[0][0]  += w0.x * x0;  P[0][1]  += w0.x * x1;  P[0][2]  += w0.x * x2;
            P[1][0]  += w0.y * x0;  P[1][1]  += w0.y * x1;  P[1][2]  += w0.y * x2;
            P[2][0]  += w0.z * x0;  P[2][1]  += w0.z * x1;  P[2][2]  += w0.z * x2;
            P[3][0]  += w0.w * x0;  P[3][1]  += w0.w * x1;  P[3][2]  += w0.w * x2;
            P[4][0]  += w4.x * x0;  P[4][1]  += w4.x * x1;  P[4][2]  += w4.x * x2;
            P[5][0]  += w4.y * x0;  P[5][1]  += w4.y * x1;  P[5][2]  += w4.y * x2;
            P[6][0]  += w4.z * x0;  P[6][1]  += w4.z * x1;  P[6][2]  += w4.z * x2;
            P[7][0]  += w4.w * x0;  P[7][1]  += w4.w * x1;  P[7][2]  += w4.w * x2;
            P[8][0]  += w8.x * x0;  P[8][1]  += w8.x * x1;  P[8][2]  += w8.x * x2;
            P[9][0]  += w8.y * x0;  P[9][1]  += w8.y * x1;  P[9][2]  += w8.y * x2;
            P[10][0] += w8.z * x0;  P[10][1] += w8.z * x1;  P[10][2] += w8.z * x2;
            P[11][0] += w8.w * x0;  P[11][1] += w8.w * x1;  P[11][2] += w8.w * x2;
        }
        __syncthreads();   // xc free for the stage in the next iteration
    }

    // write partials
    size_t blkc = (size_t)b * CPB + cblk;
    #pragma unroll
    for (int h = 0; h < NH; h++) {
        part[(blkc * NH + h) * HH + 0 * 256 + t] = P[h][0];
        part[(blkc * NH + h) * HH + 1 * 256 + t] = P[h][1];
        part[(blkc * NH + h) * HH + 2 * 256 + t] = P[h][2];
    }
    if (t < NH) { pm[blkc * NH + t] = msh[t]; pl[blkc * NH + t] = lsh[t]; }
}

// ---------------- K2: combine chunk partials -> pooled ----------------
__global__ __launch_bounds__(256) void k_comb(const float* __restrict__ part,
                                              const float* __restrict__ pm,
                                              const float* __restrict__ pl,
                                              float* __restrict__ pooled) {
    int h = blockIdx.x, b = blockIdx.y, t = threadIdx.x;
    __shared__ float fac[64];
    __shared__ float Ish;
    float mval = -1e30f, lval = 0.f;
    if (t < CPB) {
        mval = pm[((size_t)b * CPB + t) * NH + h];
        lval = pl[((size_t)b * CPB + t) * NH + h];
    }
    if (t < 64) {
        float m = mval;
        #pragma unroll
        for (int off = 1; off < 64; off <<= 1) m = fmaxf(m, __shfl_xor(m, off, 64));
        float fc = (t < CPB) ? __expf(mval - m) : 0.f;
        fac[t] = fc;
        float l = lval * fc;
        #pragma unroll
        for (int off = 1; off < 64; off <<= 1) l += __shfl_xor(l, off, 64);
        if (t == 0) Ish = 1.0f / l;
    }
    __syncthreads();
    float inv = Ish;
    #pragma unroll
    for (int kk = 0; kk < 3; kk++) {
        int col = kk * 256 + t;
        float s = 0.f;
        #pragma unroll 8
        for (int c = 0; c < CPB; c++)
            s += part[(((size_t)b * CPB + c) * NH + h) * HH + col] * fac[c];
        pooled[((size_t)b * NH + h) * HH + col] = s * inv;
    }
}

// ---------------- K3: op = W_v pooled + b_v ----------------
__global__ __launch_bounds__(256) void k_v(const float* __restrict__ pooled,
                                           const float* __restrict__ w_kv,
                                           const float* __restrict__ b_kv,
                                           float* __restrict__ op) {
    int seg = blockIdx.x, b = blockIdx.y, t = threadIdx.x;
    __shared__ __align__(16) float pv[1536];
    for (int i = t; i < 1536; i += 256)
        pv[i] = pooled[((size_t)b * NH + seg * 2) * HH + i];
    __syncthreads();
    int wave = t >> 6, lane = t & 63;
    int lh = wave >> 1;
    for (int o = 0; o < 32; o++) {
        int hd = seg * 128 + wave * 32 + o;
        const float* wr = w_kv + (size_t)(HH + hd) * HH + lane * 4;
        float s = 0.f;
        #pragma unroll
        for (int kk = 0; kk < 3; kk++) {
            float4 wv = *(const float4*)(wr + 256 * kk);
            float4 qv = *(const float4*)&pv[lh * HH + lane * 4 + 256 * kk];
            s += dot4(wv, qv);
        }
        #pragma unroll
        for (int off = 1; off < 64; off <<= 1) s += __shfl_xor(s, off, 64);
        if (lane == 0) op[(size_t)b * HH + hd] = s + b_kv[HH + hd];
    }
}

// ---------------- K4: out = gate * (W_out op + b_out) ----------------
__global__ __launch_bounds__(256) void k_fin(const float* __restrict__ op_in,
                                             const float* __restrict__ w_out,
                                             const float* __restrict__ b_out,
                                             const float* __restrict__ gate,
                                             float* __restrict__ out) {
    int seg = blockIdx.x, b = blockIdx.y, t = threadIdx.x;
    __shared__ __align__(16) float ov[HH];
    for (int i = t; i < HH; i += 256) ov[i] = op_in[(size_t)b * HH + i];
    __syncthreads();
    int wave = t >> 6, lane = t & 63;
    for (int o = 0; o < 32; o++) {
        int i = seg * 128 + wave * 32 + o;
        const float* wr = w_out + (size_t)i * HH + lane * 4;
        float s = 0.f;
        #pragma unroll
        for (int kk = 0; kk < 3; kk++) {
            float4 wv = *(const float4*)(wr + 256 * kk);
            float4 qv = *(const float4*)&ov[lane * 4 + 256 * kk];
            s += dot4(wv, qv);
        }
        #pragma unroll
        for (int off = 1; off < 64; off <<= 1) s += __shfl_xor(s, off, 64);
        if (lane == 0) out[(size_t)b * HH + i] = gate[i] * (s + b_out[i]);
    }
}

extern "C" void kernel_launch(void* const* d_in, const int* in_sizes, int n_in,
                              void* d_out, int out_size, void* d_ws, size_t ws_size,
                              hipStream_t stream) {
    const float* x      = (const float*)d_in[0];
    const float* query  = (const float*)d_in[1];
    const float* w_kv   = (const float*)d_in[2];
    const float* b_kv   = (const float*)d_in[3];
    const float* w_out  = (const float*)d_in[4];
    const float* b_out  = (const float*)d_in[5];
    const float* w_gate = (const float*)d_in[6];
    const float* b_gate = (const float*)d_in[7];
    float* ws  = (float*)d_ws;
    float* out = (float*)d_out;

    float* gate   = ws + WS_GATE;
    float* opbuf  = ws + WS_OP;
    float* pooled = ws + WS_POOLED;
    float* pm     = ws + WS_STATS;
    float* pl     = pm + (size_t)BB * CPB * NH;
    float* part   = pl + (size_t)BB * CPB * NH;

    k_pre<<<133, 256, 0, stream>>>(query, w_kv, b_kv, w_gate, b_gate, ws);
    k_fused<<<dim3(CPB, BB), 256, 0, stream>>>(x, ws, part, pm, pl);
    k_comb<<<dim3(NH, BB), 256, 0, stream>>>(part, pm, pl, pooled);
    k_v<<<dim3(6, BB), 256, 0, stream>>>(pooled, w_kv, b_kv, opbuf);
    k_fin<<<dim3(6, BB), 256, 0, stream>>>(opbuf, w_out, b_out, gate, out);
}